// Round 1
// baseline (133.849 us; speedup 1.0000x reference)
//
#include <hip/hip_runtime.h>
#include <math.h>

#ifndef M_PI
#define M_PI 3.14159265358979323846
#endif

#define L2E_ 1.4426950408889634

static __device__ __forceinline__ float fexp2(float x) {
#if __has_builtin(__builtin_amdgcn_exp2f)
  return __builtin_amdgcn_exp2f(x);
#else
  return exp2f(x);
#endif
}
static __device__ __forceinline__ float flog2(float x) {
#if __has_builtin(__builtin_amdgcn_logf)
  return __builtin_amdgcn_logf(x);
#else
  return log2f(x);
#endif
}

// ws layout (floats):
//  [0]  cB   = log2e / (2*sigma_n^2)           (u^2 coefficient)
//  [1]  cA   = log2e / sn2                      (v^2 coefficient)
//  [2]  Qmax = max over (j,n) of q2
//  [3]  Dmax = max over (j,n) of d2
//  [4]  Rmax (interior shift bound)
//  [5]  Cs2  (global constant, log2 units)
//  [6..9]   cI2[p]   interior cross coeffs
//  [10..13] bI2[p]   interior offsets
//  [32..32+768*4) table of float4 {c2, bB2, d2, 0}
//  [4096..4096+nb)  per-block partials

__global__ void setup_kernel(const float* __restrict__ eps,
                             const float* __restrict__ Iarr,
                             const float* __restrict__ Warr,
                             const float* __restrict__ psb,
                             const float* __restrict__ psn,
                             const float* __restrict__ pdd,
                             const float* __restrict__ prr,
                             float* __restrict__ ws) {
  const int tid = threadIdx.x;
  const double sb = (double)psb[0], sn = (double)psn[0];
  const double dd = (double)pdd[0], r = (double)prr[0];
  const double rho = tanh(r);
  const double sig_eff = sn * sqrt(1.0 - rho);
  const double sn2 = sn * sn * (1.0 - rho);
  const double inv_sn2 = 1.0 / sn2;
  const double inv_2snsq = 1.0 / (2.0 * sn * sn);   // uses sigma_n (lp_u part)
  // log_softmax(W), 10 entries, redundantly per thread (cheap)
  double wmax = -1e300;
  for (int k = 0; k < 10; ++k) wmax = fmax(wmax, (double)Warr[k]);
  double wsum = 0.0;
  for (int k = 0; k < 10; ++k) wsum += exp((double)Warr[k] - wmax);
  const double lse_w = wmax + log(wsum);
  const double LG = -0.12078223763524522;  // log(gamma(1.5))
  const double C0 = -log(sig_eff) - 0.5 * log(M_PI);
  const double Cs = -log(sn) - 0.5 * log(2.0 * M_PI) + C0;
  const double lnN = log(128.0);
  const int ia[6] = {0, 0, 0, 1, 1, 2};
  const int ib[6] = {1, 2, 3, 2, 3, 3};
  float4* tbl = (float4*)(ws + 32);
  __shared__ float red_q[256];
  __shared__ float red_d[256];
  float qmax = -1e30f, dmax = -1e30f;
  for (int idx = tid; idx < 768; idx += blockDim.x) {
    const int j = idx >> 7;
    const double Ia = (double)Iarr[ia[j]];
    const double Ib = (double)Iarr[ib[j]];
    const double e = (double)eps[idx];
    const double ux = e * 2.0 * dd * sb - dd * sb;
    const double arg = ux / (sqrt(2.0) * sb);
    // erfinv(erf(arg)) == arg, so G needs no erfinv
    const double In = (erf(arg) + 1.0) * 0.5 * (Ib - Ia) + Ia;
    const double G = (Ib - Ia) / sqrt(2.0 * M_PI * sb * sb) * exp(-arg * arg);
    const double lw = (double)Warr[4 + j] - lse_w;
    const double q = -log(G) - G * G * inv_sn2 + lw - lnN;
    const double c = In / (sn * sn);
    const double bB = q - In * In * inv_2snsq;
    const double d2 = 2.0 * G * inv_sn2;
    float4 t;
    t.x = (float)(c * L2E_);
    t.y = (float)(bB * L2E_);
    t.z = (float)(d2 * L2E_);
    t.w = 0.0f;
    tbl[idx] = t;
    qmax = fmaxf(qmax, (float)(q * L2E_));
    dmax = fmaxf(dmax, (float)(d2 * L2E_));
  }
  red_q[tid] = qmax;
  red_d[tid] = dmax;
  __syncthreads();
  for (int s = 128; s > 0; s >>= 1) {
    if (tid < s) {
      red_q[tid] = fmaxf(red_q[tid], red_q[tid + s]);
      red_d[tid] = fmaxf(red_d[tid], red_d[tid + s]);
    }
    __syncthreads();
  }
  if (tid == 0) {
    ws[0] = (float)(inv_2snsq * L2E_);
    ws[1] = (float)(inv_sn2 * L2E_);
    ws[2] = red_q[0];
    ws[3] = red_d[0];
    double Rmax = -1e300;
    for (int p = 0; p < 4; ++p) {
      const double Ip = (double)Iarr[p];
      const double lw = (double)Warr[p] - lse_w;
      const double bI = lw + log(2.0) - LG - 3.0 * log(sig_eff) - log(sn)
                        - 0.5 * log(2.0 * M_PI) - Cs - Ip * Ip * inv_2snsq;
      const double R = (bI + Ip * Ip * inv_2snsq) * L2E_;
      if (R > Rmax) Rmax = R;
      ws[6 + p] = (float)((Ip / (sn * sn)) * L2E_);
      ws[10 + p] = (float)(bI * L2E_);
    }
    ws[4] = (float)Rmax;
    ws[5] = (float)(Cs * L2E_);
  }
}

__launch_bounds__(256)
__global__ void main_kernel(const float* __restrict__ U, const float* __restrict__ V,
                            const float* __restrict__ ws, float* __restrict__ partials,
                            int M) {
  __shared__ float4 tbl[768];
  __shared__ float red[256];
  const int tid = threadIdx.x;
  {
    const float4* g = (const float4*)(ws + 32);
    for (int i = tid; i < 768; i += 256) tbl[i] = g[i];
  }
  const float cB = ws[0], cA = ws[1], Qmax = ws[2], Dmax = ws[3];
  const float Rmax = ws[4], Cs2 = ws[5];
  float cI[4], bI[4];
#pragma unroll
  for (int p = 0; p < 4; ++p) { cI[p] = ws[6 + p]; bI[p] = ws[10 + p]; }
  __syncthreads();
  const int m = blockIdx.x * 256 + tid;
  float lp2 = 0.0f;
  if (m < M) {
    const float u = U[m];
    const float v = V[m];
    const float l2v = flog2(v);
    const float ucB = u * u * cB;
    // analytic upper bound on the max term exponent: no overflow possible
    const float K = ucB + fmaxf(Qmax + v * Dmax, l2v + Rmax);
    const float A2 = l2v - v * v * cA - ucB;
    float accI = 0.0f;
#pragma unroll
    for (int p = 0; p < 4; ++p)
      accI += fexp2(l2v + __builtin_fmaf(u, cI[p], bI[p]) - K);
    float a1 = 0.0f, a2 = 0.0f, b1 = 0.0f, b2 = 0.0f;
#pragma unroll 4
    for (int i = 0; i < 768; i += 2) {
      const float4 t0 = tbl[i];
      const float4 t1 = tbl[i + 1];
      const float P0 = __builtin_fmaf(u, t0.x, t0.y) - K;
      const float z0 = v * t0.z;
      a1 += fexp2(P0 + z0);
      a2 += fexp2(P0 - z0);
      const float P1 = __builtin_fmaf(u, t1.x, t1.y) - K;
      const float z1 = v * t1.z;
      b1 += fexp2(P1 + z1);
      b2 += fexp2(P1 - z1);
    }
    float total = accI + (a1 - a2) + (b1 - b2);
    total = fmaxf(total, 1e-38f);  // guard impossible all-underflow tail
    lp2 = Cs2 + A2 + K + flog2(total);
  }
  red[tid] = lp2;
  __syncthreads();
  for (int s = 128; s > 0; s >>= 1) {
    if (tid < s) red[tid] += red[tid + s];
    __syncthreads();
  }
  if (tid == 0) partials[blockIdx.x] = red[0];
}

__global__ void reduce_kernel(const float* __restrict__ partials,
                              float* __restrict__ out, int nb, float scale) {
  __shared__ float red[256];
  const int tid = threadIdx.x;
  float s = 0.0f;
  for (int i = tid; i < nb; i += 256) s += partials[i];
  red[tid] = s;
  __syncthreads();
  for (int k = 128; k > 0; k >>= 1) {
    if (tid < k) red[tid] += red[tid + k];
    __syncthreads();
  }
  if (tid == 0) out[0] = red[0] * scale;
}

extern "C" void kernel_launch(void* const* d_in, const int* in_sizes, int n_in,
                              void* d_out, int out_size, void* d_ws, size_t ws_size,
                              hipStream_t stream) {
  const float* u   = (const float*)d_in[0];
  const float* v   = (const float*)d_in[1];
  const float* eps = (const float*)d_in[2];
  const float* I   = (const float*)d_in[3];
  const float* W   = (const float*)d_in[4];
  const float* sb  = (const float*)d_in[5];
  const float* sn  = (const float*)d_in[6];
  const float* dd  = (const float*)d_in[7];
  const float* rr  = (const float*)d_in[8];
  const int M = in_sizes[0];
  float* ws = (float*)d_ws;
  float* partials = ws + 4096;
  const int nb = (M + 255) / 256;

  setup_kernel<<<1, 256, 0, stream>>>(eps, I, W, sb, sn, dd, rr, ws);
  main_kernel<<<nb, 256, 0, stream>>>(u, v, ws, partials, M);
  reduce_kernel<<<1, 256, 0, stream>>>(partials, (float*)d_out, nb,
                                       -0.69314718055994531f / (float)M);
}